// Round 3
// baseline (612.489 us; speedup 1.0000x reference)
//
#include <hip/hip_runtime.h>
#include <stdint.h>

// ---------------------------------------------------------------------------
// ShiftedWindowAttention: B=32, H=W=64, C=256, heads=8, hd=32, ws=8, shift=4.
// Round-3 pipeline:
//   cvt   (weights f32->bf16)
//   bmc   (bias+mask table, 4 mask classes x 8 heads, bf16, L2-resident)
//   qkv   (per-window: gather+cvt x into LDS full-K A, 3 n-tiles of 256,
//          granule-transposed B staging, LDS-transpose epilogue)
//   attn  (per-window: S^T=K*Q^T, column softmax, P LDS, O=P*V -> AO in LDS,
//          then out-proj GEMM + merge/inv-roll scatter; AO never hits HBM)
// ---------------------------------------------------------------------------

typedef short short8 __attribute__((ext_vector_type(8)));
typedef float f32x4 __attribute__((ext_vector_type(4)));
typedef unsigned short ushort4v __attribute__((ext_vector_type(4)));

typedef __attribute__((address_space(1))) uint32_t g_u32;
typedef __attribute__((address_space(3))) uint32_t l_u32;

#define SCALE 0.17677669529663687f

__device__ __forceinline__ uint16_t f2bf(float f) {
  union { float f; uint32_t u; } c; c.f = f;
  uint32_t r = c.u + 0x7FFFu + ((c.u >> 16) & 1u);   // RNE
  return (uint16_t)(r >> 16);
}
__device__ __forceinline__ float bf2f(uint16_t b) {
  union { uint32_t u; float f; } c; c.u = ((uint32_t)b) << 16;
  return c.f;
}
__device__ __forceinline__ void g2lds16(const void* g, void* l) {
  __builtin_amdgcn_global_load_lds((const g_u32*)g, (l_u32*)l, 16, 0, 0);
}

// ---- plain f32 -> bf16 (weights)
__global__ __launch_bounds__(256) void cvt_kernel(const float* __restrict__ in,
                                                  uint16_t* __restrict__ out, int n) {
  int i = (blockIdx.x * 256 + threadIdx.x) * 8;
  if (i >= n) return;
  f32x4 a = *(const f32x4*)(in + i);
  f32x4 b = *(const f32x4*)(in + i + 4);
  short8 v;
  v[0] = (short)f2bf(a[0]); v[1] = (short)f2bf(a[1]);
  v[2] = (short)f2bf(a[2]); v[3] = (short)f2bf(a[3]);
  v[4] = (short)f2bf(b[0]); v[5] = (short)f2bf(b[1]);
  v[6] = (short)f2bf(b[2]); v[7] = (short)f2bf(b[3]);
  *(short8*)(out + i) = v;
}

// ---- bias+mask table: bmc[class][head][kk][a(16)][ni(4)] bf16 (256 KB total)
//      class = (hw==7)*2 + (ww==7); value = bias(query i=ni*16+a, key j=kk)
__global__ __launch_bounds__(256) void bmc_kernel(const float* __restrict__ pe,
                                                  uint16_t* __restrict__ bmc) {
  int bx = blockIdx.x;              // class*8 + head
  int cls = bx >> 3, head = bx & 7;
  int hw7 = cls >> 1, ww7 = cls & 1;
  int tid = threadIdx.x;
  int kk = tid >> 2, a0 = (tid & 3) * 4;
  int jy = kk >> 3, jx = kk & 7;
  int rjy = hw7 ? (1 + (jy >= 4)) : 0;
  int rjx = ww7 ? (1 + (jx >= 4)) : 0;
  int rj = rjy * 3 + rjx;
  for (int aa = 0; aa < 4; ++aa) {
    int a = a0 + aa;
    ushort4v v;
#pragma unroll
    for (int ni = 0; ni < 4; ++ni) {
      int i = ni * 16 + a;
      int iy = i >> 3, ix = i & 7;
      int riy = hw7 ? (1 + (iy >= 4)) : 0;
      int rix = ww7 ? (1 + (ix >= 4)) : 0;
      int ri = riy * 3 + rix;
      float val = (ri != rj) ? -1e30f : pe[head * 225 + (iy - jy + 7) * 15 + (ix - jx + 7)];
      v[ni] = f2bf(val);
    }
    *(ushort4v*)&bmc[(size_t)bx * 4096 + kk * 64 + a * 4] = v;
  }
}

// ---- QKV: per-window (64 tokens). A (gathered x, bf16, full K) in LDS once;
//      loop 3 n-tiles of 256; B staged granule-transposed via global_load_lds.
__global__ __launch_bounds__(256) void qkv_kernel(
    const float* __restrict__ x, const uint16_t* __restrict__ wq,
    const float* __restrict__ bqkv,
    uint16_t* __restrict__ qws, uint16_t* __restrict__ kws, uint16_t* __restrict__ vws) {
  __shared__ uint16_t A[16384];    // [64][256] bf16, XOR-swizzled granules, 32 KB
  __shared__ uint16_t SH[16384];   // B stage (16 KB) / epilogue (32 KB), shared
  const int tid = threadIdx.x, lane = tid & 63, wv = tid >> 6;
  const int quad = lane >> 4, l15 = lane & 15;
  const int w = blockIdx.x;
  const int b = w >> 6, wd = w & 63;

  // phase 1: gather + convert x window rows into LDS A
#pragma unroll
  for (int it = 0; it < 4; ++it) {
    int row = it * 16 + (tid >> 4);
    int ch = (tid & 15) * 16;
    int t = row;
    int h = (wd >> 3) * 8 + (t >> 3);
    int xx = (wd & 7) * 8 + (t & 7);
    int src = b * 4096 + (((h + 4) & 63) << 6) + ((xx + 4) & 63);
    const float* sp = x + (size_t)src * 256 + ch;
    f32x4 f0 = *(const f32x4*)sp;
    f32x4 f1 = *(const f32x4*)(sp + 4);
    f32x4 f2 = *(const f32x4*)(sp + 8);
    f32x4 f3 = *(const f32x4*)(sp + 12);
    short8 v0, v1;
    v0[0] = (short)f2bf(f0[0]); v0[1] = (short)f2bf(f0[1]);
    v0[2] = (short)f2bf(f0[2]); v0[3] = (short)f2bf(f0[3]);
    v0[4] = (short)f2bf(f1[0]); v0[5] = (short)f2bf(f1[1]);
    v0[6] = (short)f2bf(f1[2]); v0[7] = (short)f2bf(f1[3]);
    v1[0] = (short)f2bf(f2[0]); v1[1] = (short)f2bf(f2[1]);
    v1[2] = (short)f2bf(f2[2]); v1[3] = (short)f2bf(f2[3]);
    v1[4] = (short)f2bf(f3[0]); v1[5] = (short)f2bf(f3[1]);
    v1[6] = (short)f2bf(f3[2]); v1[7] = (short)f2bf(f3[3]);
    int g0 = (tid & 15) * 2;
    *(short8*)&A[row * 256 + ((g0 ^ (row & 7)) << 3)] = v0;
    *(short8*)&A[row * 256 + (((g0 + 1) ^ (row & 7)) << 3)] = v1;
  }
  __syncthreads();

  f32x4 zero = {0.f, 0.f, 0.f, 0.f};
  for (int nt = 0; nt < 3; ++nt) {
    f32x4 acc[4][4];
#pragma unroll
    for (int mi = 0; mi < 4; ++mi)
#pragma unroll
      for (int ni = 0; ni < 4; ++ni) acc[mi][ni] = zero;

    for (int ks = 0; ks < 8; ++ks) {
      int k0 = ks * 32;
      // stage B[256 rows][32 k], granule-transposed: lane -> (row=lane&15, kq=lane>>4)
#pragma unroll
      for (int j = 0; j < 4; ++j) {
        int c = wv * 4 + j;
        g2lds16(wq + (size_t)(nt * 256 + c * 16 + (lane & 15)) * 256 + k0 + (lane >> 4) * 8,
                &SH[c * 512]);
      }
      __syncthreads();
      short8 af[4], bf[4];
#pragma unroll
      for (int mi = 0; mi < 4; ++mi)
        af[mi] = *(const short8*)&A[(mi * 16 + l15) * 256 + (((ks * 4 + quad) ^ (l15 & 7)) << 3)];
#pragma unroll
      for (int ni = 0; ni < 4; ++ni)
        bf[ni] = *(const short8*)&SH[(wv * 4 + ni) * 512 + (quad * 16 + l15) * 8];
#pragma unroll
      for (int mi = 0; mi < 4; ++mi)
#pragma unroll
        for (int ni = 0; ni < 4; ++ni)
          acc[mi][ni] = __builtin_amdgcn_mfma_f32_16x16x32_bf16(af[mi], bf[ni], acc[mi][ni], 0, 0, 0);
      __syncthreads();
    }

    // epilogue: +bias, per-wave LDS transpose, vectorized q/k/v stores
    const int ng0 = nt * 256 + wv * 64;          // wave's 64 output cols
    float bq4[4];
#pragma unroll
    for (int ni = 0; ni < 4; ++ni) bq4[ni] = bqkv[ng0 + ni * 16 + l15];
    uint16_t* epi = SH + wv * 4096;

    if (nt < 2) {
      // q/k: LDS layout [t][n] swizzled
#pragma unroll
      for (int mi = 0; mi < 4; ++mi)
#pragma unroll
        for (int ni = 0; ni < 4; ++ni)
#pragma unroll
          for (int r = 0; r < 4; ++r) {
            int t = mi * 16 + quad * 4 + r, n = ni * 16 + l15;
            epi[t * 64 + ((((n >> 3) ^ (t & 7)) << 3) | (n & 7))] = f2bf(acc[mi][ni][r] + bq4[ni]);
          }
      uint16_t* dst = (nt == 0) ? qws : kws;
#pragma unroll
      for (int cc = 0; cc < 8; ++cc) {
        int chunk = cc * 64 + lane;
        int trow = chunk >> 3, part = chunk & 7;
        short8 v = *(const short8*)&epi[trow * 64 + ((part ^ (trow & 7)) << 3)];
        int ng = ng0 + part * 8, hd = (ng >> 5) & 7, d = ng & 31;
        *(short8*)&dst[(size_t)((w * 8 + hd) * 64 + trow) * 32 + d] = v;
      }
    } else {
      // v: LDS layout [n(=d)][t] (transposed), swizzled
#pragma unroll
      for (int mi = 0; mi < 4; ++mi)
#pragma unroll
        for (int ni = 0; ni < 4; ++ni)
#pragma unroll
          for (int r = 0; r < 4; ++r) {
            int t = mi * 16 + quad * 4 + r, n = ni * 16 + l15;
            epi[n * 64 + ((((t >> 3) ^ (n & 7)) << 3) | (t & 7))] = f2bf(acc[mi][ni][r] + bq4[ni]);
          }
#pragma unroll
      for (int cc = 0; cc < 8; ++cc) {
        int chunk = cc * 64 + lane;
        int drow = chunk >> 3, part = chunk & 7;
        short8 v = *(const short8*)&epi[drow * 64 + ((part ^ (drow & 7)) << 3)];
        int ng = ng0 + drow, hd = (ng >> 5) & 7, d = ng & 31;
        *(short8*)&vws[(size_t)((w * 8 + hd) * 32 + d) * 64 + part * 8] = v;
      }
    }
    __syncthreads();   // epi region overlaps B staging of next nt
  }
}

// ---- attention + out-proj, per window. AO lives in LDS only.
__global__ __launch_bounds__(256) void attn_kernel(
    const uint16_t* __restrict__ qws, const uint16_t* __restrict__ kws,
    const uint16_t* __restrict__ vws, const uint16_t* __restrict__ bmc,
    const uint16_t* __restrict__ wob, const float* __restrict__ bout,
    float* __restrict__ out) {
  __shared__ uint16_t P[4][4096];                // 8 KB per wave
  __shared__ uint16_t AO[16384];                 // [64][256] swizzled, 32 KB
  const int tid = threadIdx.x, lane = tid & 63, wv = tid >> 6;
  const int quad = lane >> 4, l15 = lane & 15;
  const int w = blockIdx.x;
  const int b = w >> 6, wd = w & 63;
  const int hw = wd >> 3, ww = wd & 7;
  const int cls = ((hw == 7) << 1) | (ww == 7);
  f32x4 zero = {0.f, 0.f, 0.f, 0.f};

  for (int hh = 0; hh < 2; ++hh) {
    const int head = wv * 2 + hh;
    const uint16_t* qb = qws + (size_t)(w * 8 + head) * 2048;
    const uint16_t* kb = kws + (size_t)(w * 8 + head) * 2048;
    const uint16_t* vb = vws + (size_t)(w * 8 + head) * 2048;
    const uint16_t* bmh = bmc + (size_t)(cls * 8 + head) * 4096;

    short8 ak[4], bq[4];
#pragma unroll
    for (int mi = 0; mi < 4; ++mi)
      ak[mi] = *(const short8*)&kb[(mi * 16 + l15) * 32 + quad * 8];
#pragma unroll
    for (int ni = 0; ni < 4; ++ni)
      bq[ni] = *(const short8*)&qb[(ni * 16 + l15) * 32 + quad * 8];

    f32x4 s[4][4];                               // S^T: row kk, col q
#pragma unroll
    for (int mi = 0; mi < 4; ++mi)
#pragma unroll
      for (int ni = 0; ni < 4; ++ni)
        s[mi][ni] = __builtin_amdgcn_mfma_f32_16x16x32_bf16(ak[mi], bq[ni], zero, 0, 0, 0);

    // scale + bias (mask folded), bf16 table, coalesced 8 B loads
#pragma unroll
    for (int mi = 0; mi < 4; ++mi)
#pragma unroll
      for (int r = 0; r < 4; ++r) {
        int kk = mi * 16 + quad * 4 + r;
        ushort4v b4 = *(const ushort4v*)&bmh[kk * 64 + l15 * 4];
#pragma unroll
        for (int ni = 0; ni < 4; ++ni)
          s[mi][ni][r] = s[mi][ni][r] * SCALE + bf2f(b4[ni]);
      }

    // softmax per column q: 16 in-lane values + 2 shfls
#pragma unroll
    for (int ni = 0; ni < 4; ++ni) {
      float mx = s[0][ni][0];
#pragma unroll
      for (int mi = 0; mi < 4; ++mi)
#pragma unroll
        for (int r = 0; r < 4; ++r) mx = fmaxf(mx, s[mi][ni][r]);
      mx = fmaxf(mx, __shfl_xor(mx, 16, 64));
      mx = fmaxf(mx, __shfl_xor(mx, 32, 64));
      float sum = 0.f;
#pragma unroll
      for (int mi = 0; mi < 4; ++mi)
#pragma unroll
        for (int r = 0; r < 4; ++r) {
          float e = __expf(s[mi][ni][r] - mx);
          s[mi][ni][r] = e;
          sum += e;
        }
      sum += __shfl_xor(sum, 16, 64);
      sum += __shfl_xor(sum, 32, 64);
      float inv = 1.f / sum;
#pragma unroll
      for (int mi = 0; mi < 4; ++mi)
#pragma unroll
        for (int r = 0; r < 4; ++r) s[mi][ni][r] *= inv;
    }

    // P[q][kk] bf16, swizzled, packed-pair writes (intra-wave only)
    uint16_t* Pw = P[wv];
#pragma unroll
    for (int mi = 0; mi < 4; ++mi)
#pragma unroll
      for (int ni = 0; ni < 4; ++ni)
#pragma unroll
        for (int rp = 0; rp < 2; ++rp) {
          int kk = mi * 16 + quad * 4 + rp * 2;
          int q = ni * 16 + l15;
          uint32_t pk = (uint32_t)f2bf(s[mi][ni][rp * 2]) |
                        ((uint32_t)f2bf(s[mi][ni][rp * 2 + 1]) << 16);
          *(uint32_t*)&Pw[q * 64 + ((((kk >> 3) ^ (q & 7)) << 3) | (kk & 7))] = pk;
        }

    // O = P @ V (V stored [d][t] = B-operand layout)
    f32x4 o[4][2];
#pragma unroll
    for (int mi = 0; mi < 4; ++mi) { o[mi][0] = zero; o[mi][1] = zero; }
#pragma unroll
    for (int ki = 0; ki < 2; ++ki) {
      short8 vf0 = *(const short8*)&vb[(l15) * 64 + ki * 32 + quad * 8];
      short8 vf1 = *(const short8*)&vb[(16 + l15) * 64 + ki * 32 + quad * 8];
#pragma unroll
      for (int mi = 0; mi < 4; ++mi) {
        int q = mi * 16 + l15;
        short8 pa = *(const short8*)&Pw[q * 64 + (((ki * 4 + quad) ^ (q & 7)) << 3)];
        o[mi][0] = __builtin_amdgcn_mfma_f32_16x16x32_bf16(pa, vf0, o[mi][0], 0, 0, 0);
        o[mi][1] = __builtin_amdgcn_mfma_f32_16x16x32_bf16(pa, vf1, o[mi][1], 0, 0, 0);
      }
    }
    // AO[t][col] swizzled
#pragma unroll
    for (int mi = 0; mi < 4; ++mi)
#pragma unroll
      for (int ni = 0; ni < 2; ++ni)
#pragma unroll
        for (int r = 0; r < 4; ++r) {
          int t = mi * 16 + quad * 4 + r;
          int col = head * 32 + ni * 16 + l15;
          AO[t * 256 + ((((col >> 3) ^ (t & 7)) << 3) | (col & 7))] = f2bf(o[mi][ni][r]);
        }
  }

  __syncthreads();

  // out-proj: out[64,256] = AO @ wo^T + bout; each wave owns 64 cols
  const int n0 = wv * 64;
  f32x4 o2[4][4];
#pragma unroll
  for (int mi = 0; mi < 4; ++mi)
#pragma unroll
    for (int ni = 0; ni < 4; ++ni) o2[mi][ni] = zero;
  for (int ks = 0; ks < 8; ++ks) {
    short8 am[4], wb[4];
#pragma unroll
    for (int mi = 0; mi < 4; ++mi) {
      int row = mi * 16 + l15;
      am[mi] = *(const short8*)&AO[row * 256 + (((ks * 4 + quad) ^ (row & 7)) << 3)];
    }
#pragma unroll
    for (int ni = 0; ni < 4; ++ni)
      wb[ni] = *(const short8*)&wob[(size_t)(n0 + ni * 16 + l15) * 256 + ks * 32 + quad * 8];
#pragma unroll
    for (int mi = 0; mi < 4; ++mi)
#pragma unroll
      for (int ni = 0; ni < 4; ++ni)
        o2[mi][ni] = __builtin_amdgcn_mfma_f32_16x16x32_bf16(am[mi], wb[ni], o2[mi][ni], 0, 0, 0);
  }
  float bo4[4];
#pragma unroll
  for (int ni = 0; ni < 4; ++ni) bo4[ni] = bout[n0 + ni * 16 + l15];
#pragma unroll
  for (int mi = 0; mi < 4; ++mi) {
#pragma unroll
    for (int r = 0; r < 4; ++r) {
      int t = mi * 16 + quad * 4 + r;
      int h = hw * 8 + (t >> 3), xx = ww * 8 + (t & 7);
      int row = (((h + 4) & 63) << 6) | ((xx + 4) & 63);   // merge + inverse roll
      float* op = out + ((size_t)b * 4096 + row) * 256 + n0;
#pragma unroll
      for (int ni = 0; ni < 4; ++ni) op[ni * 16 + l15] = o2[mi][ni][r] + bo4[ni];
    }
  }
}

extern "C" void kernel_launch(void* const* d_in, const int* in_sizes, int n_in,
                              void* d_out, int out_size, void* d_ws, size_t ws_size,
                              hipStream_t stream) {
  const float* x = (const float*)d_in[0];
  const float* w_qkv = (const float*)d_in[1];
  const float* b_qkv = (const float*)d_in[2];
  const float* w_out = (const float*)d_in[3];
  const float* b_out = (const float*)d_in[4];
  const float* pos_enc = (const float*)d_in[5];
  float* out = (float*)d_out;

  uint8_t* ws = (uint8_t*)d_ws;
  uint16_t* wqb = (uint16_t*)(ws);                 //    393,216 B
  uint16_t* wob = (uint16_t*)(ws + 393216);        //    131,072 B
  uint16_t* bmc = (uint16_t*)(ws + 524288);        //    262,144 B
  uint16_t* qws = (uint16_t*)(ws + 786432);        // 67,108,864 B
  uint16_t* kws = (uint16_t*)(ws + 67895296);      // 67,108,864 B
  uint16_t* vws = (uint16_t*)(ws + 135004160);     // 67,108,864 B -> 202,113,024 B

  cvt_kernel<<<96, 256, 0, stream>>>(w_qkv, wqb, 196608);
  cvt_kernel<<<32, 256, 0, stream>>>(w_out, wob, 65536);
  bmc_kernel<<<32, 256, 0, stream>>>(pos_enc, bmc);
  qkv_kernel<<<2048, 256, 0, stream>>>(x, wqb, b_qkv, qws, kws, vws);
  attn_kernel<<<2048, 256, 0, stream>>>(qws, kws, vws, bmc, wob, b_out, out);
}